// Round 1
// baseline (14853.137 us; speedup 1.0000x reference)
//
#include <hip/hip_runtime.h>
#include <hip/hip_fp16.h>

#define BB 16
#define TT 1024
#define DD 1024
#define SS 512
#define KK 3072   // [x | ctx | h]

#define NBLK 256
#define NTHR 512

// d_out layout (floats): context [0,16384) | alignment [16384, 8404992) | termination [8404992,+16)
#define OUT_ALIGN 16384
#define OUT_TERM  8404992

typedef __attribute__((ext_vector_type(8))) short short8;     // 8 bf16 (4 VGPRs)
typedef __attribute__((ext_vector_type(4))) float floatx4;    // MFMA C/D
typedef __attribute__((ext_vector_type(2))) _Float16 half2v;  // v_dot2 operand

struct KParams {
  const float* x;      // (B,T,D) fp32
  const float* mem;    // (B,S,D) fp32
  const int*   lens;
  const float* W_ih;   // (4D, 2D)
  const float* W_hh;   // (4D, D)
  const float* b_ih;
  const float* b_hh;
  const float* Wg_w;   // (48, D)
  const float* Wg_b;
  float* out;
  unsigned* bar;        // flag barrier region (zeroed each call)
  unsigned short* xc0;  // (B, 3072) bf16 recurrent state [x|ctx|h]
  unsigned short* xc1;
  unsigned* wgbf;       // Wg_w packed as bf16 pairs (48*512 u32), built once in-kernel
};

__device__ __forceinline__ float sigf(float v) {
  return __builtin_amdgcn_rcpf(1.0f + __expf(-v));
}
__device__ __forceinline__ float tanhfast(float v) {  // exp/rcp tanh, no libm
  float a = fabsf(v);
  float e = __expf(-2.0f * a);
  float r = (1.0f - e) * __builtin_amdgcn_rcpf(1.0f + e);
  return v < 0.0f ? -r : r;
}

__device__ __forceinline__ unsigned short f2bf(float f) {  // RNE fp32->bf16
  unsigned u = __float_as_uint(f);
  return (unsigned short)((u + 0x7FFFu + ((u >> 16) & 1u)) >> 16);
}
__device__ __forceinline__ float bf2f(unsigned short h) {
  return __uint_as_float(((unsigned)h) << 16);
}
__device__ __forceinline__ unsigned pack2bf(float a, float b) {
  return (unsigned)f2bf(a) | ((unsigned)f2bf(b) << 16);
}

// Agent-scope relaxed atomics = plain loads/stores at the coherence point (LLC).
__device__ __forceinline__ void cstore_u32(unsigned* p2, unsigned v) {
  __hip_atomic_store(p2, v, __ATOMIC_RELAXED, __HIP_MEMORY_SCOPE_AGENT);
}
__device__ __forceinline__ unsigned cload_u32(const unsigned* p2) {
  return __hip_atomic_load(p2, __ATOMIC_RELAXED, __HIP_MEMORY_SCOPE_AGENT);
}
__device__ __forceinline__ unsigned long long cload_u64(const unsigned long long* p2) {
  return __hip_atomic_load(p2, __ATOMIC_RELAXED, __HIP_MEMORY_SCOPE_AGENT);
}

// LDS-only barrier: s_barrier without the vmcnt(0) drain __syncthreads implies.
// Outstanding global (coherent) loads stay in flight across it — that is the point:
// the prefetched A-fragments ride through all of phase C's stage barriers.
__device__ __forceinline__ void lds_barrier() {
  asm volatile("s_waitcnt lgkmcnt(0)\n\ts_barrier" ::: "memory");
}

// Decentralized 1-hop grid barrier: every block stores its epoch flag, then every
// block's threads 0..255 directly poll all 256 flags (no block-0 aggregate + release
// hop — saves ~1 LLC round trip per barrier vs the previous 2-hop design).
// The leading __syncthreads drains vmcnt(0): all prior coherent data stores are
// globally visible before the flag store (release), and monotonic epochs make
// re-poisoning/reset unnecessary.
__device__ __forceinline__ void grid_barrier(unsigned* bar, unsigned ep, int blk) {
  __syncthreads();
  if (threadIdx.x == 0) cstore_u32(&bar[64 + blk * 32], ep);
  if (threadIdx.x < NBLK) {
    while (cload_u32(&bar[64 + threadIdx.x * 32]) < ep) __builtin_amdgcn_s_sleep(1);
  }
  __syncthreads();
}

union UF { unsigned long long u[2]; short8 s; };
struct AF8 { UF f[8]; };

// x-part (chunks 0..3) + h-part (chunks 4..7) fragment loads. K per wave is realigned:
// wave w owns x[w*128,+128) | ctx[w*128,+128) | h[w*128,+128) so the ctx-dependent
// third is the ONLY thing left on the post-barE critical path.
__device__ __forceinline__ void xh_load(const unsigned short* xc, int ab, AF8& A) {
  const unsigned long long* xb = (const unsigned long long*)xc + ab;
#pragma unroll
  for (int s2 = 0; s2 < 4; ++s2) {
    A.f[s2].u[0]     = cload_u64(xb + s2 * 8);
    A.f[s2].u[1]     = cload_u64(xb + s2 * 8 + 1);
    A.f[4 + s2].u[0] = cload_u64(xb + 512 + s2 * 8);
    A.f[4 + s2].u[1] = cload_u64(xb + 512 + s2 * 8 + 1);
  }
}
__device__ __forceinline__ void xh_mfma(const AF8& A, const short8* bfr,
                                        floatx4& A0, floatx4& A1) {
  floatx4 a0 = {0.f, 0.f, 0.f, 0.f}, a1 = {0.f, 0.f, 0.f, 0.f};
#pragma unroll
  for (int s2 = 0; s2 < 4; s2 += 2) {
    a0 = __builtin_amdgcn_mfma_f32_16x16x32_bf16(A.f[s2].s,     bfr[s2],     a0, 0, 0, 0);
    a1 = __builtin_amdgcn_mfma_f32_16x16x32_bf16(A.f[s2 + 1].s, bfr[s2 + 1], a1, 0, 0, 0);
    a0 = __builtin_amdgcn_mfma_f32_16x16x32_bf16(A.f[4 + s2].s,     bfr[8 + s2],     a0, 0, 0, 0);
    a1 = __builtin_amdgcn_mfma_f32_16x16x32_bf16(A.f[4 + s2 + 1].s, bfr[8 + s2 + 1], a1, 0, 0, 0);
  }
  A0 = a0; A1 = a1;
}

__global__ __launch_bounds__(NTHR, 2) void tts_kernel(KParams p) {
  extern __shared__ char smem[];
  half2v* memsh2 = (half2v*)smem;  // [256 s-pairs][64 d] fp16x2, 64 KiB

  __shared__ float redC[8 * 4 * 65 + 4];  // wave-partial C tiles
  __shared__ unsigned hshu[8 * 65];       // phase-C h (bf16 pairs), +1 pad word/row
  __shared__ float php[384];              // phi partials
  __shared__ float alsh[16], ksish[16], invbsh[16];
  __shared__ float Rsh[513];              // Rsh[s+1]=R(s); Rsh[0]=R(-1)
  __shared__ half2v wsh2[256];            // w(s) packed in s-pairs
  __shared__ float ctxp[8][64];
  __shared__ float bsh48[48];             // Wg_b

  const int t    = threadIdx.x;
  const int blk  = blockIdx.x;
  const int lane = t & 63;
  const int w    = t >> 6;     // wave id [0,8)
  const int bbt  = blk & 15;   // batch this block serves in phase C
  const int dc   = blk >> 4;   // 64-wide d-chunk for ctx / x-copy

  // ---- one-time: B-fragments (weights) into registers as bf16, realigned K ----
  // chunk ki: region r3=ki>>2 (0=x,1=ctx,2=h), sub=ki&3; k0 = r3*1024 + w*128 + sub*32
  short8 bfr[12];
  {
    const int n = lane & 15;
    const int r = (n & 3) * 1024 + blk * 4 + (n >> 2);
    const int q = lane >> 4;
#pragma unroll
    for (int ki = 0; ki < 12; ++ki) {
      short8 v;
      const int k0 = (ki >> 2) * 1024 + w * 128 + (ki & 3) * 32 + q * 8;
#pragma unroll
      for (int j = 0; j < 8; ++j) {
        int k = k0 + j;
        float wv = (k < 2048) ? p.W_ih[(size_t)r * 2048 + k]
                              : p.W_hh[(size_t)r * 1024 + (k - 2048)];
        v[j] = (short)f2bf(wv);
      }
      bfr[ki] = v;
    }
  }
  // ---- one-time: biases ----
  float biasreg[4] = {0.f, 0.f, 0.f, 0.f};
  if (t < 64) {
    int dl = t & 3;
#pragma unroll
    for (int g = 0; g < 4; ++g) {
      int r = g * 1024 + blk * 4 + dl;
      biasreg[g] = p.b_ih[r] + p.b_hh[r];
    }
  }
  if (t < 48) bsh48[t] = p.Wg_b[t];
  // ---- one-time: memory[bbt, :, dc*64..+64) -> LDS as half2 s-pairs ----
  {
    int dl = t & 63, sp = t >> 6;
    for (int pr = sp; pr < 256; pr += 8) {
      const float* mp = p.mem + (size_t)bbt * SS * DD + (size_t)(2 * pr) * DD + dc * 64 + dl;
      half2v v;
      v.x = (_Float16)mp[0];
      v.y = (_Float16)mp[DD];
      memsh2[pr * 64 + dl] = v;
    }
  }
  // ---- one-time: xc0 = [x_0 | 0 | 0] ----
  if (t < 32) {
    int k = dc * 64 + 2 * t;
    const float* xs = p.x + (size_t)bbt * TT * DD + k;
    cstore_u32((unsigned*)(p.xc0 + bbt * KK + k), pack2bf(xs[0], xs[1]));
    cstore_u32((unsigned*)(p.xc0 + bbt * KK + 1024 + k), 0u);
    cstore_u32((unsigned*)(p.xc0 + bbt * KK + 2048 + k), 0u);
  }
  // ---- one-time: Wg_w fp32 -> bf16 pairs in workspace (halves per-step L2 traffic
  //      of the phi stage: 192KB -> 96KB per block per step) ----
  if (blk == 0) {
    for (int i = t; i < 48 * 512; i += NTHR)
      cstore_u32(&p.wgbf[i], pack2bf(p.Wg_w[2 * i], p.Wg_w[2 * i + 1]));
  }

  float c_val = 0.0f;  // LSTM cell state: thread t<64 owns (b=t>>2, d=blk*4+(t&3))
  unsigned ep = 0;
  unsigned short* xc_cur = p.xc0;
  unsigned short* xc_nxt = p.xc1;
  const int ab = ((lane & 15) * KK + w * 128 + (lane >> 4) * 8) >> 2;  // u64 frag base

  grid_barrier(p.bar, ++ep, blk);

  // Pre-loop: x_0 + h_{-1}(=0) gate contributions carried into step 0's phase A.
  floatx4 accXH0, accXH1;
  {
    AF8 a;
    xh_load(xc_cur, ab, a);
    xh_mfma(a, bfr, accXH0, accXH1);
  }

  for (int tstep = 0; tstep < TT; ++tstep) {
    // ================= Phase A: ctx-part MFMA + LSTM pointwise =================
    // Only the ctx third of K is on the post-barE path; x/h parts were carried in.
    {
      const unsigned long long* xb = (const unsigned long long*)xc_cur + ab;
      UF afc[4];
#pragma unroll
      for (int s2 = 0; s2 < 4; ++s2) {
        afc[s2].u[0] = cload_u64(xb + 256 + s2 * 8);
        afc[s2].u[1] = cload_u64(xb + 256 + s2 * 8 + 1);
      }
      floatx4 a0 = accXH0, a1 = accXH1;
      a0 = __builtin_amdgcn_mfma_f32_16x16x32_bf16(afc[0].s, bfr[4], a0, 0, 0, 0);
      a1 = __builtin_amdgcn_mfma_f32_16x16x32_bf16(afc[1].s, bfr[5], a1, 0, 0, 0);
      a0 = __builtin_amdgcn_mfma_f32_16x16x32_bf16(afc[2].s, bfr[6], a0, 0, 0, 0);
      a1 = __builtin_amdgcn_mfma_f32_16x16x32_bf16(afc[3].s, bfr[7], a1, 0, 0, 0);
      a0 += a1;
#pragma unroll
      for (int reg = 0; reg < 4; ++reg)
        redC[(w * 4 + reg) * 65 + lane] = a0[reg];
    }
    lds_barrier();
    if (t < 64) {  // pointwise LSTM for (b = t>>2, dl = t&3); h packed via shfl
      int b = t >> 2, dl = t & 3;
      float gate[4];
#pragma unroll
      for (int g = 0; g < 4; ++g) {
        int ls = (b >> 2) * 16 + (dl * 4 + g);
        float s = biasreg[g];
#pragma unroll
        for (int w2 = 0; w2 < 8; ++w2) s += redC[(w2 * 4 + (b & 3)) * 65 + ls];
        gate[g] = s;
      }
      c_val = sigf(gate[1]) * c_val + sigf(gate[0]) * tanhfast(gate[2]);
      float hv = sigf(gate[3]) * tanhfast(c_val);
      float hn = __shfl_down(hv, 1, 64);
      if ((t & 1) == 0)
        cstore_u32((unsigned*)(xc_nxt + b * KK + 2048 + blk * 4 + dl), pack2bf(hv, hn));
    } else if (t < 96) {
      if (tstep + 1 < TT) {  // prefetch x_{t+1} into xc_nxt (read at this step's phase C)
        int k = dc * 64 + 2 * (t - 64);
        const float* xs = p.x + (size_t)bbt * TT * DD + (size_t)(tstep + 1) * DD + k;
        cstore_u32((unsigned*)(xc_nxt + bbt * KK + k), pack2bf(xs[0], xs[1]));
      }
    }
    grid_barrier(p.bar, ++ep, blk);  // barH: h_t (and x_{t+1}) globally visible

    // ============ Phase C: phi -> window -> ctx; overlap next-step x/h MFMA ============
    // (b) issue h staging load first (feeds the critical phi chain), then the
    //     next-step x/h fragment loads — they stay in flight across the lgkm-only
    //     stage barriers and are consumed by MFMAs at the end of the phase.
    unsigned hword = cload_u32((const unsigned*)(xc_nxt + bbt * KK + 2048) + t);
    AF8 afx;
    xh_load(xc_nxt, ab, afx);
    hshu[(t >> 6) * 65 + (t & 63)] = hword;
    lds_barrier();
    if (t < 384) {  // phi partials: m = t>>3, part = t&7 (128 k each), bf16 weights
      int m = t >> 3, part = t & 7;
      const unsigned* wgp = p.wgbf + m * 512 + part * 64;
      const unsigned* hrow = hshu + part * 65;
      float s0 = 0.f, s1 = 0.f, s2 = 0.f, s3 = 0.f;
#pragma unroll 4
      for (int i = 0; i < 64; i += 4) {
        unsigned u0 = hrow[i],     g0 = wgp[i];
        unsigned u1 = hrow[i + 1], g1 = wgp[i + 1];
        unsigned u2 = hrow[i + 2], g2 = wgp[i + 2];
        unsigned u3 = hrow[i + 3], g3 = wgp[i + 3];
        s0 += bf2f((unsigned short)u0) * bf2f((unsigned short)g0)
            + bf2f((unsigned short)(u0 >> 16)) * bf2f((unsigned short)(g0 >> 16));
        s1 += bf2f((unsigned short)u1) * bf2f((unsigned short)g1)
            + bf2f((unsigned short)(u1 >> 16)) * bf2f((unsigned short)(g1 >> 16));
        s2 += bf2f((unsigned short)u2) * bf2f((unsigned short)g2)
            + bf2f((unsigned short)(u2 >> 16)) * bf2f((unsigned short)(g2 >> 16));
        s3 += bf2f((unsigned short)u3) * bf2f((unsigned short)g3)
            + bf2f((unsigned short)(u3 >> 16)) * bf2f((unsigned short)(g3 >> 16));
      }
      php[t] = (s0 + s1) + (s2 + s3);
    }
    lds_barrier();
    if (t < 64) {  // merged: phi reduce + softmax + exps + R(-1), all in wave 0
      float s = 0.f;
      if (t < 48) {
        s = bsh48[t];
#pragma unroll
        for (int i = 0; i < 8; ++i) s += php[t * 8 + i];
      }
      // softmax within each aligned 16-lane group (meaningful for lanes 32..47)
      float mx = s;
#pragma unroll
      for (int o = 1; o < 16; o <<= 1) mx = fmaxf(mx, __shfl_xor(mx, o, 64));
      float e = __expf(s - mx);
      float sm = e;
#pragma unroll
      for (int o = 1; o < 16; o <<= 1) sm += __shfl_xor(sm, o, 64);
      float alpha_v = e * __builtin_amdgcn_rcpf(sm);
      float ksi_v   = __expf(s);
      float invb_v  = __expf(-s);
      if (t >= 32) { if (t < 48) alsh[t - 32] = alpha_v; }
      else if (t < 16) ksish[t] = ksi_v;
      else invbsh[t - 16] = invb_v;
      // R(-1) on lanes 48..63 (lane 48+m handles mixture m), xor-reduced in-group
      int m = t & 15;
      float am = __shfl(alpha_v, 32 + m, 64);
      float km = __shfl(ksi_v, m, 64);
      float bm = __shfl(invb_v, 16 + m, 64);
      float term = am * sigf((-0.5f - km) * bm);
#pragma unroll
      for (int o = 1; o < 16; o <<= 1) term += __shfl_xor(term, o, 64);
      if (t == 48) Rsh[0] = term;
    }
    lds_barrier();
    {  // R(s) + w(s)=R(s)-R(s-1) via in-wave shuffles; pack wsh2; alignment store
      float su = (float)t;
      float rv0 = 0.f, rv1 = 0.f;
#pragma unroll
      for (int m = 0; m < 16; m += 2) {
        rv0 += alsh[m]     * sigf((su + 0.5f - ksish[m])     * invbsh[m]);
        rv1 += alsh[m + 1] * sigf((su + 0.5f - ksish[m + 1]) * invbsh[m + 1]);
      }
      float rv = rv0 + rv1;
      float rvp = __shfl_up(rv, 1, 64);   // invalid at lane 0 — fixed next stage
      float rvn = __shfl_down(rv, 1, 64);
      Rsh[t + 1] = rv;
      if ((t & 1) == 0) {
        half2v v2;
        v2.x = (_Float16)(rv - rvp);
        v2.y = (_Float16)(rvn - rv);
        wsh2[t >> 1] = v2;
      }
      if (dc == 0 && (t & 63) != 0)
        p.out[OUT_ALIGN + ((size_t)bbt * TT + tstep) * SS + t] = rv - rvp;
    }
    lds_barrier();
    {  // ctx partials; wave-boundary w pairs recomputed from Rsh (lane-0 shfl gap)
      if (dc == 0 && t < 8)
        p.out[OUT_ALIGN + ((size_t)bbt * TT + tstep) * SS + 64 * t] =
            Rsh[64 * t + 1] - Rsh[64 * t];
      if (tstep == TT - 1 && dc == 0 && t == 0)
        p.out[OUT_TERM + bbt] = 1.0f - Rsh[p.lens[bbt]];
      int dl = t & 63, sp = t >> 6;
      float b0 = Rsh[64 * sp], b1 = Rsh[64 * sp + 1], b2 = Rsh[64 * sp + 2];
      half2v w0;
      w0.x = (_Float16)(b1 - b0);
      w0.y = (_Float16)(b2 - b1);
      float s0 = __builtin_amdgcn_fdot2(memsh2[(sp * 32) * 64 + dl], w0, 0.f, false);
      float s1 = 0.f;
#pragma unroll
      for (int q = 1; q < 32; ++q) {
        int pr = sp * 32 + q;
        float v = __builtin_amdgcn_fdot2(memsh2[pr * 64 + dl], wsh2[pr],
                                         (q & 1) ? s1 : s0, false);
        if (q & 1) s1 = v; else s0 = v;
      }
      ctxp[sp][dl] = s0 + s1;
    }
    lds_barrier();
    if (t < 64) {  // ctx reduce + coherent store (+ context output at last step)
      float cv = 0.f;
#pragma unroll
      for (int pp = 0; pp < 8; ++pp) cv += ctxp[pp][t];
      if (tstep == TT - 1) p.out[bbt * DD + dc * 64 + t] = cv;
      float cvn = __shfl_down(cv, 1, 64);
      if ((t & 1) == 0)
        cstore_u32((unsigned*)(xc_nxt + bbt * KK + 1024 + dc * 64 + t), pack2bf(cv, cvn));
    }
    // next-step x/h gate MFMAs (register-only; fragments loaded at phase C top).
    // sched_barrier keeps them from being hoisted up into the attention stages.
    __builtin_amdgcn_sched_barrier(0);
    xh_mfma(afx, bfr, accXH0, accXH1);
    grid_barrier(p.bar, ++ep, blk);  // barE: ctx_t globally visible

    unsigned short* tmp = xc_cur; xc_cur = xc_nxt; xc_nxt = tmp;
  }
}

extern "C" void kernel_launch(void* const* d_in, const int* in_sizes, int n_in,
                              void* d_out, int out_size, void* d_ws, size_t ws_size,
                              hipStream_t stream) {
  (void)in_sizes; (void)n_in; (void)out_size; (void)ws_size;
  KParams p;
  p.x    = (const float*)d_in[0];
  p.mem  = (const float*)d_in[1];
  p.lens = (const int*)d_in[2];
  p.W_ih = (const float*)d_in[3];
  p.W_hh = (const float*)d_in[4];
  p.b_ih = (const float*)d_in[5];
  p.b_hh = (const float*)d_in[6];
  p.Wg_w = (const float*)d_in[7];
  p.Wg_b = (const float*)d_in[8];
  p.out  = (float*)d_out;
  p.bar  = (unsigned*)d_ws;
  p.xc0  = (unsigned short*)((char*)d_ws + 36864);
  p.xc1  = (unsigned short*)((char*)d_ws + 36864 + BB * KK * 2);
  p.wgbf = (unsigned*)((char*)d_ws + 36864 + 2 * BB * KK * 2);

  hipMemsetAsync(d_ws, 0, 36864, stream);  // zero barrier flags every call

  const unsigned dynLds = 65536;  // half2 memory slice
  hipFuncSetAttribute((const void*)tts_kernel, hipFuncAttributeMaxDynamicSharedMemorySize,
                      (int)dynLds);

  void* args[] = { &p };
  hipLaunchCooperativeKernel((const void*)tts_kernel, dim3(NBLK), dim3(NTHR), args, dynLds,
                             stream);
}